// Round 3
// baseline (1044.946 us; speedup 1.0000x reference)
//
#include <hip/hip_runtime.h>
#include <hip/hip_bf16.h>

// GNN message passing: gather(x[src],x[tgt],ef) -> MLP(112->128->128->48) -> scatter-mean.
// R3: (a) prefix-sum alloc via block scan + 1 atomic/block (was: 100K atomics on ONE
// address, ~170us serialized); (b) place writes a single int4/edge; (c) mlp_kernel
// software-pipelines the gather: next tile's 28 float4s prefetched into VGPRs and
// issued before the MFMA section, hiding random-gather latency under compute.

#define NN 100000
#define NE 1600000
#define NF 48
#define TOT 112
#define HID 128
#define NTILE 6250  // NE/256

typedef __attribute__((ext_vector_type(8))) short short8;
typedef __attribute__((ext_vector_type(4))) float floatx4;

__device__ __forceinline__ unsigned short f2bf(float f) {
    union { float f; unsigned u; } v; v.f = f;
    unsigned u = v.u;
    return (unsigned short)((u + 0x7FFFu + ((u >> 16) & 1u)) >> 16);  // RNE
}

// ---- prep: W fp32 [k][n] -> WT bf16 [n][k], k padded to 128
__global__ void prep_kernel(const float* __restrict__ W1, const float* __restrict__ W2,
                            const float* __restrict__ W3,
                            unsigned short* __restrict__ wt1, unsigned short* __restrict__ wt2,
                            unsigned short* __restrict__ wt3) {
    int idx = blockIdx.x * 256 + threadIdx.x;
    if (idx < 16384) {
        int n = idx >> 7, k = idx & 127;
        wt1[idx] = (k < TOT) ? f2bf(W1[k * HID + n]) : (unsigned short)0;
    } else if (idx < 32768) {
        int j = idx - 16384; int n = j >> 7, k = j & 127;
        wt2[j] = f2bf(W2[k * HID + n]);
    } else if (idx < 38912) {
        int j = idx - 32768; int n = j >> 7, k = j & 127;
        wt3[j] = f2bf(W3[k * NF + n]);
    }
}

__global__ void hist_kernel(const int* __restrict__ ei, int* __restrict__ cnt) {
    int e = blockIdx.x * 256 + threadIdx.x;  // NE exact
    atomicAdd(cnt + ei[NE + e], 1);
}

// block-level inclusive scan + one atomic per block for the base -> exclusive offsets.
// cross-block order irrelevant: ranges are disjoint either way.
__global__ void scan_kernel(const int* __restrict__ cnt, int* __restrict__ off,
                            int* __restrict__ counter) {
    __shared__ int sd[256];
    __shared__ int sbase;
    int tid = threadIdx.x;
    int n = blockIdx.x * 256 + tid;
    int v = (n < NN) ? cnt[n] : 0;
    sd[tid] = v;
    __syncthreads();
#pragma unroll
    for (int d = 1; d < 256; d <<= 1) {
        int t = (tid >= d) ? sd[tid - d] : 0;
        __syncthreads();
        sd[tid] += t;
        __syncthreads();
    }
    if (tid == 255) sbase = atomicAdd(counter, sd[255]);
    __syncthreads();
    if (n < NN) off[n] = sbase + sd[tid] - v;  // exclusive
}

__global__ void place_kernel(const int* __restrict__ ei, int* __restrict__ off,
                             int4* __restrict__ srt) {
    int e = blockIdx.x * 256 + threadIdx.x;  // NE exact
    int t = ei[NE + e];
    int p = atomicAdd(off + t, 1);  // off is consumed here (dead after)
    srt[p] = make_int4(e, ei[e], t, 0);
}

// swizzled LDS frag helper: row stride 256B, 16B granules, g ^= row&15
__device__ __forceinline__ const short8* frag_ptr(const unsigned short* base, int row, int s,
                                                  int lane15, int quad) {
    return (const short8*)((const char*)base + row * 256 + (((s * 4 + quad) ^ lane15) << 4));
}

__device__ __forceinline__ void layer16(const unsigned short* __restrict__ lw,
                                        unsigned short* __restrict__ lact,
                                        const float* __restrict__ bias,
                                        int m0, int l15, int q) {
    short8 a[4];
#pragma unroll
    for (int s = 0; s < 4; ++s) a[s] = *frag_ptr(lact, m0 + l15, s, l15, q);
    floatx4 acc[8];
#pragma unroll
    for (int nt = 0; nt < 8; ++nt) acc[nt] = (floatx4){0.f, 0.f, 0.f, 0.f};
#pragma unroll
    for (int nt = 0; nt < 8; ++nt)
#pragma unroll
        for (int s = 0; s < 4; ++s) {
            short8 b = *frag_ptr(lw, nt * 16 + l15, s, l15, q);
            acc[nt] = __builtin_amdgcn_mfma_f32_16x16x32_bf16(a[s], b, acc[nt], 0, 0, 0);
        }
#pragma unroll
    for (int nt = 0; nt < 8; ++nt) {
        int n = nt * 16 + l15;
        float bv = bias[n];
#pragma unroll
        for (int r = 0; r < 4; ++r) {
            int row = m0 + q * 4 + r;
            float hv = fmaxf(acc[nt][r] + bv, 0.0f);
            *(unsigned short*)((char*)lact + row * 256 + (((n >> 3) ^ (row & 15)) << 4) +
                               ((n & 7) << 1)) = f2bf(hv);
        }
    }
}

// issue the gather loads for one tile into registers (7 float4/thread + tgt for tid<256)
__device__ __forceinline__ void prefetch_tile(const float* __restrict__ x,
                                              const float* __restrict__ ef,
                                              const int4* __restrict__ srt,
                                              int p0, int tid, float4* pf, int* pft) {
#pragma unroll
    for (int j = 0; j < 7; ++j) {
        int i = tid + j * 1024;
        int el = i / 28, part = i - el * 28;
        const int4* s4 = srt + p0 + el;
        const float4* gp;
        if (part < 12)      gp = (const float4*)(x + 48 * (size_t)s4->y) + part;
        else if (part < 24) gp = (const float4*)(x + 48 * (size_t)s4->z) + (part - 12);
        else                gp = (const float4*)(ef + 16 * (size_t)s4->x) + (part - 24);
        pf[j] = *gp;
    }
    if (tid < 256) *pft = srt[p0 + tid].z;
}

__launch_bounds__(1024, 4)
__global__ void mlp_kernel(const float* __restrict__ x, const float* __restrict__ ef,
                           const int4* __restrict__ srt,
                           const unsigned short* __restrict__ wt1,
                           const unsigned short* __restrict__ wt2,
                           const unsigned short* __restrict__ wt3,
                           const float* __restrict__ b1, const float* __restrict__ b2,
                           float* __restrict__ out_acc) {
    __shared__ __align__(16) unsigned short lw1[128 * 128];
    __shared__ __align__(16) unsigned short lw2[128 * 128];
    __shared__ __align__(16) unsigned short lw3[48 * 128];
    __shared__ __align__(16) unsigned short lact[256 * 128];  // 64KB; fp32 msg aliases
    __shared__ float lb[256];
    __shared__ int ltgt[256];
    __shared__ int seg_start[257];
    __shared__ int seg_tgt[256];
    __shared__ int nseg;

    const int tid = threadIdx.x;
    float* lmsg = (float*)lact;  // row stride 64 floats (256B): stays in own slab rows

    const uint4* s1 = (const uint4*)wt1;
    for (int i = tid; i < 2048; i += 1024) {
        int n = i >> 4, g = i & 15;
        *(uint4*)((char*)lw1 + n * 256 + ((g ^ (n & 15)) << 4)) = s1[i];
    }
    const uint4* s2 = (const uint4*)wt2;
    for (int i = tid; i < 2048; i += 1024) {
        int n = i >> 4, g = i & 15;
        *(uint4*)((char*)lw2 + n * 256 + ((g ^ (n & 15)) << 4)) = s2[i];
    }
    const uint4* s3 = (const uint4*)wt3;
    if (tid < 768) {
        int n = tid >> 4, g = tid & 15;
        *(uint4*)((char*)lw3 + n * 256 + ((g ^ (n & 15)) << 4)) = s3[tid];
    }
    if (tid < 256) lb[tid] = (tid < 128) ? b1[tid] : b2[tid - 128];

    const int l15 = tid & 15;
    const int q = (tid & 63) >> 4;
    const int ln = tid & 63;
    const int wave = tid >> 6;
    const int m0 = wave * 16;

    float4 pf[7];
    int pft = 0;
    prefetch_tile(x, ef, srt, blockIdx.x * 256, tid, pf, &pft);

    for (int tile = blockIdx.x; tile < NTILE; tile += gridDim.x) {
        __syncthreads();  // prev tile's reduce done (covers weight staging on iter 0)
        // ---- store prefetched gather -> bf16 swizzled lact
#pragma unroll
        for (int j = 0; j < 7; ++j) {
            int i = tid + j * 1024;
            int el = i / 28, part = i - el * 28;
            float4 v = pf[j];
            ushort4 h4;
            h4.x = f2bf(v.x); h4.y = f2bf(v.y); h4.z = f2bf(v.z); h4.w = f2bf(v.w);
            int gran = part >> 1;
            *(ushort4*)((char*)lact + el * 256 + ((gran ^ (el & 15)) << 4) +
                        ((part & 1) << 3)) = h4;
        }
        if (tid < 512) {  // zero-pad k=112..127
            int el = tid >> 1, g = 14 + (tid & 1);
            uint4 z = {0, 0, 0, 0};
            *(uint4*)((char*)lact + el * 256 + ((g ^ (el & 15)) << 4)) = z;
        }
        if (tid < 256) ltgt[tid] = pft;
        __syncthreads();
        // ---- issue next tile's gather NOW; lands during MFMA below
        int next = tile + gridDim.x;
        if (next < NTILE) prefetch_tile(x, ef, srt, next * 256, tid, pf, &pft);
        // ---- 3 layers, wave-private 16-row slab
        layer16(lw1, lact, lb, m0, l15, q);
        layer16(lw2, lact, lb + 128, m0, l15, q);
        short8 a3[4];
#pragma unroll
        for (int s = 0; s < 4; ++s) a3[s] = *frag_ptr(lact, m0 + l15, s, l15, q);
        floatx4 acc3[3];
#pragma unroll
        for (int nt = 0; nt < 3; ++nt) acc3[nt] = (floatx4){0.f, 0.f, 0.f, 0.f};
#pragma unroll
        for (int nt = 0; nt < 3; ++nt)
#pragma unroll
            for (int s = 0; s < 4; ++s) {
                short8 b = *frag_ptr(lw3, nt * 16 + l15, s, l15, q);
                acc3[nt] = __builtin_amdgcn_mfma_f32_16x16x32_bf16(a3[s], b, acc3[nt], 0, 0, 0);
            }
        // fp32 msg into own slab rows (b3 deferred to finalize)
#pragma unroll
        for (int nt = 0; nt < 3; ++nt) {
            int col = nt * 16 + l15;
#pragma unroll
            for (int r = 0; r < 4; ++r) lmsg[(m0 + q * 4 + r) * 64 + col] = acc3[nt][r];
        }
        // ---- wave 0: enumerate target runs
        if (wave == 0) {
            int base = 0;
#pragma unroll
            for (int c = 0; c < 4; ++c) {
                int p = c * 64 + ln;
                int t = ltgt[p];
                int flag = (p == 0) || (t != ltgt[p - 1]);
                unsigned long long mask = __ballot(flag);
                int sid = base + __popcll(mask & ((1ull << ln) - 1ull));
                if (flag) { seg_start[sid] = p; seg_tgt[sid] = t; }
                base += __popcll(mask);
            }
            if (ln == 0) nseg = base;
            seg_start[(ln == 0) ? base : 256] = 256;  // sentinel
        }
        __syncthreads();
        // ---- segment reduce + one atomic per (segment, feature)
        if (ln < 48) {
            for (int s = wave; s < nseg; s += 16) {
                int a = seg_start[s], bnd = seg_start[s + 1];
                float s0 = 0.f, s1 = 0.f, s2 = 0.f, s3 = 0.f;
                const float* mcol = lmsg + ln;
                int p = a;
                for (; p + 3 < bnd; p += 4) {
                    s0 += mcol[p * 64]; s1 += mcol[(p + 1) * 64];
                    s2 += mcol[(p + 2) * 64]; s3 += mcol[(p + 3) * 64];
                }
                for (; p < bnd; ++p) s0 += mcol[p * 64];
                float sum = (s0 + s1) + (s2 + s3);
                atomicAdd(out_acc + 48 * (size_t)seg_tgt[s] + ln, sum);
            }
        }
    }
}

__global__ void finalize_kernel(const float* __restrict__ x, const int* __restrict__ cnt,
                                const float* __restrict__ b3, float* __restrict__ out) {
    int i = blockIdx.x * 256 + threadIdx.x;  // NN*48 exact
    float c = (float)cnt[i / 48];
    float upd = (c > 0.f) ? (out[i] / c + b3[i % 48]) : 0.f;
    out[i] = x[i] + upd;
}

extern "C" void kernel_launch(void* const* d_in, const int* in_sizes, int n_in,
                              void* d_out, int out_size, void* d_ws, size_t ws_size,
                              hipStream_t stream) {
    const float* x  = (const float*)d_in[0];
    const int*   ei = (const int*)d_in[1];
    const float* ef = (const float*)d_in[2];
    const float* W1 = (const float*)d_in[3];
    const float* b1 = (const float*)d_in[4];
    const float* W2 = (const float*)d_in[5];
    const float* b2 = (const float*)d_in[6];
    const float* W3 = (const float*)d_in[7];
    const float* b3 = (const float*)d_in[8];
    float* out = (float*)d_out;

    char* ws = (char*)d_ws;
    int* cnt     = (int*)ws;                    // 400000 B (pad 409600)
    int* off     = (int*)(ws + 409600);         // 400000 B (pad 409600)
    int* counter = (int*)(ws + 819200);         // 256 B
    unsigned short* wt1 = (unsigned short*)(ws + 819456);
    unsigned short* wt2 = wt1 + 16384;
    unsigned short* wt3 = wt2 + 16384;          // ends 819456+77824=897280
    int4* srt = (int4*)(ws + 901120);           // 25.6 MB

    hipMemsetAsync(out, 0, (size_t)out_size * sizeof(float), stream);
    hipMemsetAsync(cnt, 0, (size_t)NN * sizeof(int), stream);
    hipMemsetAsync(counter, 0, sizeof(int), stream);
    prep_kernel<<<152, 256, 0, stream>>>(W1, W2, W3, wt1, wt2, wt3);
    hist_kernel<<<NTILE, 256, 0, stream>>>(ei, cnt);
    scan_kernel<<<391, 256, 0, stream>>>(cnt, off, counter);
    place_kernel<<<NTILE, 256, 0, stream>>>(ei, off, srt);
    mlp_kernel<<<256, 1024, 0, stream>>>(x, ef, srt, wt1, wt2, wt3, b1, b2, out);
    finalize_kernel<<<NN * NF / 256, 256, 0, stream>>>(x, cnt, b3, out);
}

// Round 5
// 678.716 us; speedup vs baseline: 1.5396x; 1.5396x over previous
//
#include <hip/hip_runtime.h>
#include <hip/hip_bf16.h>

// GNN message passing: gather(x[src],x[tgt],ef) -> MLP(112->128->128->48) -> scatter-mean.
// R5 = R4 structure with the race fixed: TRANSPOSED MFMA (h^T = W^T * act^T), weights =
// A-operand (LDS), activations = B-operand. D-layout col=edge,row=feat -> packed b64
// activation stores. Wave owns a 16-edge slab; gather+L1+L2+L3 barrier-free via LDS
// rotation ea->tmp->ea->tmp. CRITICAL INVARIANT: every per-wave LDS row (act AND msg)
// is 256B so each wave stays inside its own 4KB slab. R4's bug: lmsg stride was 52
// floats (208B) -> wave 7's msg rows aliased wave 5/6's live h1 -> NaN. Stride is 64.

#define NN 100000
#define NE 1600000
#define NF 48
#define TOT 112
#define HID 128
#define TILE 128
#define NTILE 12500  // NE/128

typedef __attribute__((ext_vector_type(8))) short short8;
typedef __attribute__((ext_vector_type(4))) float floatx4;

__device__ __forceinline__ unsigned short f2bf(float f) {
    union { float f; unsigned u; } v; v.f = f;
    unsigned u = v.u;
    return (unsigned short)((u + 0x7FFFu + ((u >> 16) & 1u)) >> 16);  // RNE
}
__device__ __forceinline__ unsigned pack2bf(float a, float b) {
    return (unsigned)f2bf(a) | ((unsigned)f2bf(b) << 16);
}

// ---- prep: W fp32 [k][n] -> WT bf16 [n][k], k padded to 128
__global__ void prep_kernel(const float* __restrict__ W1, const float* __restrict__ W2,
                            const float* __restrict__ W3,
                            unsigned short* __restrict__ wt1, unsigned short* __restrict__ wt2,
                            unsigned short* __restrict__ wt3) {
    int idx = blockIdx.x * 256 + threadIdx.x;
    if (idx < 16384) {
        int n = idx >> 7, k = idx & 127;
        wt1[idx] = (k < TOT) ? f2bf(W1[k * HID + n]) : (unsigned short)0;
    } else if (idx < 32768) {
        int j = idx - 16384; int n = j >> 7, k = j & 127;
        wt2[j] = f2bf(W2[k * HID + n]);
    } else if (idx < 38912) {
        int j = idx - 32768; int n = j >> 7, k = j & 127;
        wt3[j] = f2bf(W3[k * NF + n]);
    }
}

__global__ void hist_kernel(const int* __restrict__ ei, int* __restrict__ cnt) {
    int e = blockIdx.x * 256 + threadIdx.x;  // NE exact
    atomicAdd(cnt + ei[NE + e], 1);
}

// block scan + one atomic/block -> exclusive offsets; also fills tgt_s runs.
__global__ void scan_fill_kernel(const int* __restrict__ cnt, int* __restrict__ off,
                                 int* __restrict__ counter, int* __restrict__ tgt_s) {
    __shared__ int sd[256];
    __shared__ int sbase;
    int tid = threadIdx.x;
    int n = blockIdx.x * 256 + tid;
    int v = (n < NN) ? cnt[n] : 0;
    sd[tid] = v;
    __syncthreads();
#pragma unroll
    for (int d = 1; d < 256; d <<= 1) {
        int t = (tid >= d) ? sd[tid - d] : 0;
        __syncthreads();
        sd[tid] += t;
        __syncthreads();
    }
    if (tid == 255) sbase = atomicAdd(counter, sd[255]);
    __syncthreads();
    if (n < NN) {
        int o = sbase + sd[tid] - v;  // exclusive
        off[n] = o;
        for (int j = 0; j < v; ++j) tgt_s[o + j] = n;
    }
}

__global__ void place_kernel(const int* __restrict__ ei, int* __restrict__ off,
                             int2* __restrict__ srt) {
    int e = blockIdx.x * 256 + threadIdx.x;  // NE exact
    int t = ei[NE + e];
    int p = atomicAdd(off + t, 1);  // off consumed (dead after this kernel)
    srt[p] = make_int2(e, ei[e]);   // {eid, src}
}

// swizzled LDS frag helper: row stride 256B, 16B granules, g ^= row&15
__device__ __forceinline__ const short8* frag_ptr(const unsigned short* base, int row, int s,
                                                  int lane15, int quad) {
    return (const short8*)((const char*)base + row * 256 + (((s * 4 + quad) ^ lane15) << 4));
}

__launch_bounds__(512, 2)
__global__ void gemm_kernel(const float* __restrict__ x, const float* __restrict__ ef,
                            const int2* __restrict__ srt, const int* __restrict__ tgt_s,
                            const unsigned short* __restrict__ wt1,
                            const unsigned short* __restrict__ wt2,
                            const unsigned short* __restrict__ wt3,
                            const float* __restrict__ b1, const float* __restrict__ b2,
                            float* __restrict__ out_acc) {
    __shared__ __align__(16) unsigned short lw1[128 * 128];  // 32 KB
    __shared__ __align__(16) unsigned short lw2[128 * 128];  // 32 KB
    __shared__ __align__(16) unsigned short lw3[48 * 128];   // 12 KB
    __shared__ __align__(16) unsigned short ea[TILE * 128];  // 32 KB: E, then h2
    __shared__ __align__(16) unsigned short tmp[TILE * 128]; // 32 KB: h1, then msg fp32[128][64]
    __shared__ float lb1[128], lb2[128];
    __shared__ int ltgt[TILE];
    __shared__ int seg_start[TILE + 4];
    __shared__ int seg_tgt[TILE];
    __shared__ int nseg;

    const int tid = threadIdx.x;
    // ---- stage weights swizzled (once per persistent block)
    const uint4* s1 = (const uint4*)wt1;
    for (int i = tid; i < 2048; i += 512) {
        int n = i >> 4, g = i & 15;
        *(uint4*)((char*)lw1 + n * 256 + ((g ^ (n & 15)) << 4)) = s1[i];
    }
    const uint4* s2 = (const uint4*)wt2;
    for (int i = tid; i < 2048; i += 512) {
        int n = i >> 4, g = i & 15;
        *(uint4*)((char*)lw2 + n * 256 + ((g ^ (n & 15)) << 4)) = s2[i];
    }
    const uint4* s3 = (const uint4*)wt3;
    for (int i = tid; i < 768; i += 512) {
        int n = i >> 4, g = i & 15;
        *(uint4*)((char*)lw3 + n * 256 + ((g ^ (n & 15)) << 4)) = s3[i];
    }
    if (tid < 128) lb1[tid] = b1[tid];
    else if (tid < 256) lb2[tid - 128] = b2[tid - 128];
    __syncthreads();

    const int l15 = tid & 15;
    const int q = (tid & 63) >> 4;
    const int ln = tid & 63;
    const int wave = tid >> 6;
    const int el = wave * 16 + l15;   // tile-local edge row owned by this lane
    float* lmsg = (float*)tmp;        // [128][64] fp32: 256B rows == slab rows (invariant!)

    for (int tile = blockIdx.x; tile < NTILE; tile += gridDim.x) {
        const int e0 = tile * TILE;
        if (tid < TILE) ltgt[tid] = tgt_s[e0 + tid];
        // ---- gather own slab row: lane covers parts {q, q+4, ..., q+24} of edge el
        {
            int e = e0 + el;
            int2 es = srt[e];            // {eid, src}  (4 lanes redundant; L1$ broadcast)
            int tv = tgt_s[e];
            float4 v[7];
#pragma unroll
            for (int j = 0; j < 7; ++j) {
                int p = q + 4 * j;
                const float4* gp;
                if (p < 12)      gp = (const float4*)(x + 48 * (size_t)es.y) + p;
                else if (p < 24) gp = (const float4*)(x + 48 * (size_t)tv) + (p - 12);
                else             gp = (const float4*)(ef + 16 * (size_t)es.x) + (p - 24);
                v[j] = *gp;
            }
#pragma unroll
            for (int j = 0; j < 7; ++j) {
                int p = q + 4 * j;
                int gsrc = p >> 1;
                uint2 h = make_uint2(pack2bf(v[j].x, v[j].y), pack2bf(v[j].z, v[j].w));
                *(uint2*)((char*)ea + el * 256 + (((gsrc ^ l15)) << 4) + ((p & 1) << 3)) = h;
            }
            int pz = 28 + q;  // zero-pad cols 112..127 (granules 14,15)
            *(uint2*)((char*)ea + el * 256 + ((((pz >> 1) ^ l15)) << 4) + ((pz & 1) << 3)) =
                make_uint2(0u, 0u);
        }
        // ---- L1: tmp(h1) = relu(W1^T * E^T)   [all in-wave: no barrier]
        {
            short8 bf[4];
#pragma unroll
            for (int s = 0; s < 4; ++s) bf[s] = *frag_ptr(ea, el, s, l15, q);
#pragma unroll
            for (int mt = 0; mt < 8; ++mt) {
                floatx4 acc = (floatx4){0.f, 0.f, 0.f, 0.f};
#pragma unroll
                for (int s = 0; s < 4; ++s) {
                    short8 a = *frag_ptr(lw1, mt * 16 + l15, s, l15, q);
                    acc = __builtin_amdgcn_mfma_f32_16x16x32_bf16(a, bf[s], acc, 0, 0, 0);
                }
                int f0 = mt * 16 + q * 4;
                const float4 bv = *(const float4*)(lb1 + f0);
                uint2 h = make_uint2(
                    pack2bf(fmaxf(acc[0] + bv.x, 0.f), fmaxf(acc[1] + bv.y, 0.f)),
                    pack2bf(fmaxf(acc[2] + bv.z, 0.f), fmaxf(acc[3] + bv.w, 0.f)));
                *(uint2*)((char*)tmp + el * 256 + (((f0 >> 3) ^ l15) << 4) + ((q & 1) << 3)) = h;
            }
        }
        // ---- L2: ea(h2) = relu(W2^T * h1^T)   (E dead after L1 bf-reads)
        {
            short8 bf[4];
#pragma unroll
            for (int s = 0; s < 4; ++s) bf[s] = *frag_ptr(tmp, el, s, l15, q);
#pragma unroll
            for (int mt = 0; mt < 8; ++mt) {
                floatx4 acc = (floatx4){0.f, 0.f, 0.f, 0.f};
#pragma unroll
                for (int s = 0; s < 4; ++s) {
                    short8 a = *frag_ptr(lw2, mt * 16 + l15, s, l15, q);
                    acc = __builtin_amdgcn_mfma_f32_16x16x32_bf16(a, bf[s], acc, 0, 0, 0);
                }
                int f0 = mt * 16 + q * 4;
                const float4 bv = *(const float4*)(lb2 + f0);
                uint2 h = make_uint2(
                    pack2bf(fmaxf(acc[0] + bv.x, 0.f), fmaxf(acc[1] + bv.y, 0.f)),
                    pack2bf(fmaxf(acc[2] + bv.z, 0.f), fmaxf(acc[3] + bv.w, 0.f)));
                *(uint2*)((char*)ea + el * 256 + (((f0 >> 3) ^ l15) << 4) + ((q & 1) << 3)) = h;
            }
        }
        // ---- L3: msg fp32 into own slab rows of tmp (h1 dead); b3 added in finalize
        {
            short8 bf[4];
#pragma unroll
            for (int s = 0; s < 4; ++s) bf[s] = *frag_ptr(ea, el, s, l15, q);
#pragma unroll
            for (int mt = 0; mt < 3; ++mt) {
                floatx4 acc = (floatx4){0.f, 0.f, 0.f, 0.f};
#pragma unroll
                for (int s = 0; s < 4; ++s) {
                    short8 a = *frag_ptr(lw3, mt * 16 + l15, s, l15, q);
                    acc = __builtin_amdgcn_mfma_f32_16x16x32_bf16(a, bf[s], acc, 0, 0, 0);
                }
                int f0 = mt * 16 + q * 4;
                *(float4*)(lmsg + el * 64 + f0) = *(float4*)&acc;  // 256B rows: own slab
            }
        }
        __syncthreads();  // msg complete across waves
        // ---- wave 0: enumerate target runs (2 chunks of 64)
        if (wave == 0) {
            int base = 0;
#pragma unroll
            for (int c = 0; c < 2; ++c) {
                int p = c * 64 + ln;
                int t = ltgt[p];
                int flag = (p == 0) || (t != ltgt[p - 1]);
                unsigned long long mask = __ballot(flag);
                int sid = base + __popcll(mask & ((1ull << ln) - 1ull));
                if (flag) { seg_start[sid] = p; seg_tgt[sid] = t; }
                base += __popcll(mask);
            }
            if (ln == 0) { nseg = base; seg_start[base] = TILE; }
        }
        __syncthreads();
        // ---- segment reduce + one atomic per (segment, feature)
        if (ln < 48) {
            for (int s = wave; s < nseg; s += 8) {
                int a = seg_start[s], bnd = seg_start[s + 1];
                float s0 = 0.f, s1f = 0.f;
                const float* mcol = lmsg + ln;
                int p = a;
                for (; p + 1 < bnd; p += 2) { s0 += mcol[p * 64]; s1f += mcol[(p + 1) * 64]; }
                if (p < bnd) s0 += mcol[p * 64];
                atomicAdd(out_acc + 48 * (size_t)seg_tgt[s] + ln, s0 + s1f);
            }
        }
        __syncthreads();  // reduce done before next tile overwrites tmp/ltgt
    }
}

__global__ void finalize_kernel(const float* __restrict__ x, const int* __restrict__ cnt,
                                const float* __restrict__ b3, float* __restrict__ out) {
    int i = blockIdx.x * 256 + threadIdx.x;  // NN*48 exact
    float c = (float)cnt[i / 48];
    float upd = (c > 0.f) ? (out[i] / c + b3[i % 48]) : 0.f;
    out[i] = x[i] + upd;
}

extern "C" void kernel_launch(void* const* d_in, const int* in_sizes, int n_in,
                              void* d_out, int out_size, void* d_ws, size_t ws_size,
                              hipStream_t stream) {
    const float* x  = (const float*)d_in[0];
    const int*   ei = (const int*)d_in[1];
    const float* ef = (const float*)d_in[2];
    const float* W1 = (const float*)d_in[3];
    const float* b1 = (const float*)d_in[4];
    const float* W2 = (const float*)d_in[5];
    const float* b2 = (const float*)d_in[6];
    const float* W3 = (const float*)d_in[7];
    const float* b3 = (const float*)d_in[8];
    float* out = (float*)d_out;

    char* ws = (char*)d_ws;
    int* cnt     = (int*)ws;                    // 400000 B (pad 409600)
    int* off     = (int*)(ws + 409600);         // 400000 B (pad 409600)
    int* counter = (int*)(ws + 819200);         // 256 B
    unsigned short* wt1 = (unsigned short*)(ws + 819456);
    unsigned short* wt2 = wt1 + 16384;
    unsigned short* wt3 = wt2 + 16384;          // ends ~897 KB
    int* tgt_s = (int*)(ws + 901120);           // 6.4 MB
    int2* srt  = (int2*)(ws + 901120 + 6553600);// 12.8 MB

    hipMemsetAsync(out, 0, (size_t)out_size * sizeof(float), stream);
    hipMemsetAsync(cnt, 0, (size_t)NN * sizeof(int), stream);
    hipMemsetAsync(counter, 0, sizeof(int), stream);
    prep_kernel<<<152, 256, 0, stream>>>(W1, W2, W3, wt1, wt2, wt3);
    hist_kernel<<<6250, 256, 0, stream>>>(ei, cnt);
    scan_fill_kernel<<<391, 256, 0, stream>>>(cnt, off, counter, tgt_s);
    place_kernel<<<6250, 256, 0, stream>>>(ei, off, srt);
    gemm_kernel<<<256, 512, 0, stream>>>(x, ef, srt, tgt_s, wt1, wt2, wt3, b1, b2, out);
    finalize_kernel<<<NN * NF / 256, 256, 0, stream>>>(x, cnt, b3, out);
}

// Round 6
// 615.697 us; speedup vs baseline: 1.6972x; 1.1024x over previous
//
#include <hip/hip_runtime.h>
#include <hip/hip_bf16.h>

// GNN message passing: gather(x[src],x[tgt],ef) -> MLP(112->128->128->48) -> scatter-mean.
// R6: transposed MFMA (h^T = W^T * act^T), weights A-operand from LDS, acts B-operand.
// TILE=256, 8 waves x 32-edge slabs: weight frags amortized over 2 edge groups
// (3.1 b128 reads/edge vs 4.75 in R5). Layers run IN-PLACE in one 64KB act buffer:
// all input frags are register-loaded before any output store; same-wave LDS ops are
// processed in order, so no WAR hazard; slabs are wave-private so no cross-wave hazard.
// All LDS rows are 256B and XOR-swizzled by (granule ^ row&15) INCLUDING the fp32 msg
// tile (R5 left msg unswizzled -> 16-way conflicts, 26.4M cycles).
// Aux: srt is int4{eid,src,tgt} written by place; scan no longer fills tgt_s (serial
// divergent loop removed); cnt for finalize from hist.

#define NN 100000
#define NE 1600000
#define NF 48
#define TOT 112
#define HID 128
#define TILE 256
#define NTILE 6250  // NE/256

typedef __attribute__((ext_vector_type(8))) short short8;
typedef __attribute__((ext_vector_type(4))) float floatx4;

__device__ __forceinline__ unsigned short f2bf(float f) {
    union { float f; unsigned u; } v; v.f = f;
    unsigned u = v.u;
    return (unsigned short)((u + 0x7FFFu + ((u >> 16) & 1u)) >> 16);  // RNE
}
__device__ __forceinline__ unsigned pack2bf(float a, float b) {
    return (unsigned)f2bf(a) | ((unsigned)f2bf(b) << 16);
}

// ---- prep: W fp32 [k][n] -> WT bf16 [n][k], k padded to 128
__global__ void prep_kernel(const float* __restrict__ W1, const float* __restrict__ W2,
                            const float* __restrict__ W3,
                            unsigned short* __restrict__ wt1, unsigned short* __restrict__ wt2,
                            unsigned short* __restrict__ wt3) {
    int idx = blockIdx.x * 256 + threadIdx.x;
    if (idx < 16384) {
        int n = idx >> 7, k = idx & 127;
        wt1[idx] = (k < TOT) ? f2bf(W1[k * HID + n]) : (unsigned short)0;
    } else if (idx < 32768) {
        int j = idx - 16384; int n = j >> 7, k = j & 127;
        wt2[j] = f2bf(W2[k * HID + n]);
    } else if (idx < 38912) {
        int j = idx - 32768; int n = j >> 7, k = j & 127;
        wt3[j] = f2bf(W3[k * NF + n]);
    }
}

__global__ void hist_kernel(const int* __restrict__ ei, int* __restrict__ cnt) {
    int e = blockIdx.x * 256 + threadIdx.x;  // NE exact
    atomicAdd(cnt + ei[NE + e], 1);
}

// pure block scan + one atomic/block -> exclusive offsets
__global__ void scan_kernel(const int* __restrict__ cnt, int* __restrict__ off,
                            int* __restrict__ counter) {
    __shared__ int sd[256];
    __shared__ int sbase;
    int tid = threadIdx.x;
    int n = blockIdx.x * 256 + tid;
    int v = (n < NN) ? cnt[n] : 0;
    sd[tid] = v;
    __syncthreads();
#pragma unroll
    for (int d = 1; d < 256; d <<= 1) {
        int t = (tid >= d) ? sd[tid - d] : 0;
        __syncthreads();
        sd[tid] += t;
        __syncthreads();
    }
    if (tid == 255) sbase = atomicAdd(counter, sd[255]);
    __syncthreads();
    if (n < NN) off[n] = sbase + sd[tid] - v;  // exclusive
}

__global__ void place_kernel(const int* __restrict__ ei, int* __restrict__ off,
                             int4* __restrict__ srt) {
    int e = blockIdx.x * 256 + threadIdx.x;  // NE exact
    int t = ei[NE + e];
    int p = atomicAdd(off + t, 1);  // off consumed (dead after this kernel)
    srt[p] = make_int4(e, ei[e], t, 0);  // {eid, src, tgt}
}

// swizzled LDS frag helper: row stride 256B, 16B granules, granule g stored at g^(row&15)
__device__ __forceinline__ const short8* frag_ptr(const unsigned short* base, int row, int s,
                                                  int lane15, int quad) {
    return (const short8*)((const char*)base + row * 256 + (((s * 4 + quad) ^ lane15) << 4));
}

__launch_bounds__(512, 2)
__global__ void gemm_kernel(const float* __restrict__ x, const float* __restrict__ ef,
                            const int4* __restrict__ srt,
                            const unsigned short* __restrict__ wt1,
                            const unsigned short* __restrict__ wt2,
                            const unsigned short* __restrict__ wt3,
                            const float* __restrict__ b1, const float* __restrict__ b2,
                            float* __restrict__ out_acc) {
    __shared__ __align__(16) unsigned short lw1[128 * 128];  // 32 KB
    __shared__ __align__(16) unsigned short lw2[128 * 128];  // 32 KB
    __shared__ __align__(16) unsigned short lw3[48 * 128];   // 12 KB
    __shared__ __align__(16) unsigned short ea[TILE * 128];  // 64 KB: E -> h1 -> h2 -> msg
    __shared__ float lb1[128], lb2[128];
    __shared__ int ltgt[TILE];
    __shared__ int seg_start[TILE + 4];
    __shared__ int seg_tgt[TILE];
    __shared__ int nseg;

    const int tid = threadIdx.x;
    // ---- stage weights swizzled (once per persistent block)
    const uint4* s1 = (const uint4*)wt1;
    for (int i = tid; i < 2048; i += 512) {
        int n = i >> 4, g = i & 15;
        *(uint4*)((char*)lw1 + n * 256 + ((g ^ (n & 15)) << 4)) = s1[i];
    }
    const uint4* s2 = (const uint4*)wt2;
    for (int i = tid; i < 2048; i += 512) {
        int n = i >> 4, g = i & 15;
        *(uint4*)((char*)lw2 + n * 256 + ((g ^ (n & 15)) << 4)) = s2[i];
    }
    const uint4* s3 = (const uint4*)wt3;
    for (int i = tid; i < 768; i += 512) {
        int n = i >> 4, g = i & 15;
        *(uint4*)((char*)lw3 + n * 256 + ((g ^ (n & 15)) << 4)) = s3[i];
    }
    if (tid < 128) lb1[tid] = b1[tid];
    else if (tid < 256) lb2[tid - 128] = b2[tid - 128];
    __syncthreads();

    const int l15 = tid & 15;
    const int q = (tid & 63) >> 4;
    const int ln = tid & 63;
    const int wave = tid >> 6;
    const int sub = ln & 1;             // gather: 2 lanes per edge row
    const int grow = wave * 32 + (ln >> 1);  // gather: tile-local edge row (0..255)
    const int gl15 = grow & 15;
    float* lmsg = (float*)ea;

    for (int tile = blockIdx.x; tile < NTILE; tile += gridDim.x) {
        const int e0 = tile * TILE;
        if (tid < TILE) ltgt[tid] = srt[e0 + tid].z;
        // ---- gather: lane covers parts p = 2j+sub (j=0..13) of edge row `grow`
        {
            int4 es = srt[e0 + grow];  // {eid, src, tgt}
            float4 v[14];
#pragma unroll
            for (int j = 0; j < 14; ++j) {
                int p = 2 * j + sub;
                const float4* gp;
                if (p < 12)      gp = (const float4*)(x + 48 * (size_t)es.y) + p;
                else if (p < 24) gp = (const float4*)(x + 48 * (size_t)es.z) + (p - 12);
                else             gp = (const float4*)(ef + 16 * (size_t)es.x) + (p - 24);
                v[j] = *gp;
            }
#pragma unroll
            for (int j = 0; j < 14; ++j) {
                uint2 h = make_uint2(pack2bf(v[j].x, v[j].y), pack2bf(v[j].z, v[j].w));
                *(uint2*)((char*)ea + grow * 256 + ((j ^ gl15) << 4) + (sub << 3)) = h;
            }
            // zero-pad cols 112..127: granules 14,15 (one uint4 per lane)
            *(uint4*)((char*)ea + grow * 256 + (((14 + sub) ^ gl15) << 4)) =
                make_uint4(0u, 0u, 0u, 0u);
        }
        // ---- L1, L2 in-place (frags registered before stores; same-wave DS in order)
#pragma unroll
        for (int layer = 0; layer < 2; ++layer) {
            const unsigned short* lw = layer ? lw2 : lw1;
            const float* lb = layer ? lb2 : lb1;
            short8 bf[2][4];
#pragma unroll
            for (int gi = 0; gi < 2; ++gi)
#pragma unroll
                for (int s = 0; s < 4; ++s)
                    bf[gi][s] = *frag_ptr(ea, (wave * 2 + gi) * 16 + l15, s, l15, q);
#pragma unroll
            for (int mt = 0; mt < 8; ++mt) {
                floatx4 a0 = (floatx4){0.f, 0.f, 0.f, 0.f};
                floatx4 a1 = (floatx4){0.f, 0.f, 0.f, 0.f};
#pragma unroll
                for (int s = 0; s < 4; ++s) {
                    short8 a = *frag_ptr(lw, mt * 16 + l15, s, l15, q);
                    a0 = __builtin_amdgcn_mfma_f32_16x16x32_bf16(a, bf[0][s], a0, 0, 0, 0);
                    a1 = __builtin_amdgcn_mfma_f32_16x16x32_bf16(a, bf[1][s], a1, 0, 0, 0);
                }
                int f0 = mt * 16 + q * 4;
                const float4 bv = *(const float4*)(lb + f0);
                uint2 h0 = make_uint2(
                    pack2bf(fmaxf(a0[0] + bv.x, 0.f), fmaxf(a0[1] + bv.y, 0.f)),
                    pack2bf(fmaxf(a0[2] + bv.z, 0.f), fmaxf(a0[3] + bv.w, 0.f)));
                uint2 h1 = make_uint2(
                    pack2bf(fmaxf(a1[0] + bv.x, 0.f), fmaxf(a1[1] + bv.y, 0.f)),
                    pack2bf(fmaxf(a1[2] + bv.z, 0.f), fmaxf(a1[3] + bv.w, 0.f)));
                int gran = 2 * mt + (q >> 1), off8 = (q & 1) << 3;
                *(uint2*)((char*)ea + (wave * 32 + l15) * 256 + ((gran ^ l15) << 4) + off8) = h0;
                *(uint2*)((char*)ea + (wave * 32 + 16 + l15) * 256 + ((gran ^ l15) << 4) + off8) = h1;
            }
        }
        // ---- L3: msg fp32 in-place (h2 dead after frag reads); b3 added in finalize
        {
            short8 bf[2][4];
#pragma unroll
            for (int gi = 0; gi < 2; ++gi)
#pragma unroll
                for (int s = 0; s < 4; ++s)
                    bf[gi][s] = *frag_ptr(ea, (wave * 2 + gi) * 16 + l15, s, l15, q);
#pragma unroll
            for (int mt = 0; mt < 3; ++mt) {
                floatx4 a0 = (floatx4){0.f, 0.f, 0.f, 0.f};
                floatx4 a1 = (floatx4){0.f, 0.f, 0.f, 0.f};
#pragma unroll
                for (int s = 0; s < 4; ++s) {
                    short8 a = *frag_ptr(lw3, mt * 16 + l15, s, l15, q);
                    a0 = __builtin_amdgcn_mfma_f32_16x16x32_bf16(a, bf[0][s], a0, 0, 0, 0);
                    a1 = __builtin_amdgcn_mfma_f32_16x16x32_bf16(a, bf[1][s], a1, 0, 0, 0);
                }
                int gran = mt * 4 + q;  // fp32: granule = (f0*4B)/16 = mt*4+q, full 16B
                *(float4*)((char*)ea + (wave * 32 + l15) * 256 + ((gran ^ l15) << 4)) =
                    *(float4*)&a0;
                *(float4*)((char*)ea + (wave * 32 + 16 + l15) * 256 + ((gran ^ l15) << 4)) =
                    *(float4*)&a1;
            }
        }
        __syncthreads();  // msg + ltgt complete across waves
        // ---- wave 0: enumerate target runs (4 chunks of 64)
        if (wave == 0) {
            int base = 0;
#pragma unroll
            for (int c = 0; c < 4; ++c) {
                int p = c * 64 + ln;
                int t = ltgt[p];
                int flag = (p == 0) || (t != ltgt[p - 1]);
                unsigned long long mask = __ballot(flag);
                int sid = base + __popcll(mask & ((1ull << ln) - 1ull));
                if (flag) { seg_start[sid] = p; seg_tgt[sid] = t; }
                base += __popcll(mask);
            }
            if (ln == 0) { nseg = base; seg_start[base] = TILE; }
        }
        __syncthreads();
        // ---- segment reduce + one atomic per (segment, feature); swizzled msg reads
        if (ln < 48) {
            const int gcol = ln >> 2, coff = (ln & 3) << 2;
            for (int s = wave; s < nseg; s += 8) {
                int a = seg_start[s], bnd = seg_start[s + 1];
                float s0 = 0.f, s1f = 0.f;
                int p = a;
                for (; p + 1 < bnd; p += 2) {
                    s0  += *(const float*)((const char*)ea + p * 256 +
                                           ((gcol ^ (p & 15)) << 4) + coff);
                    s1f += *(const float*)((const char*)ea + (p + 1) * 256 +
                                           ((gcol ^ ((p + 1) & 15)) << 4) + coff);
                }
                if (p < bnd)
                    s0 += *(const float*)((const char*)ea + p * 256 +
                                          ((gcol ^ (p & 15)) << 4) + coff);
                atomicAdd(out_acc + 48 * (size_t)seg_tgt[s] + ln, s0 + s1f);
            }
        }
        __syncthreads();  // reduce done before next tile overwrites ea/ltgt/segs
    }
}

__global__ void finalize_kernel(const float* __restrict__ x, const int* __restrict__ cnt,
                                const float* __restrict__ b3, float* __restrict__ out) {
    int i = blockIdx.x * 256 + threadIdx.x;  // NN*48 exact
    float c = (float)cnt[i / 48];
    float upd = (c > 0.f) ? (out[i] / c + b3[i % 48]) : 0.f;
    out[i] = x[i] + upd;
}

extern "C" void kernel_launch(void* const* d_in, const int* in_sizes, int n_in,
                              void* d_out, int out_size, void* d_ws, size_t ws_size,
                              hipStream_t stream) {
    const float* x  = (const float*)d_in[0];
    const int*   ei = (const int*)d_in[1];
    const float* ef = (const float*)d_in[2];
    const float* W1 = (const float*)d_in[3];
    const float* b1 = (const float*)d_in[4];
    const float* W2 = (const float*)d_in[5];
    const float* b2 = (const float*)d_in[6];
    const float* W3 = (const float*)d_in[7];
    const float* b3 = (const float*)d_in[8];
    float* out = (float*)d_out;

    char* ws = (char*)d_ws;
    int* cnt     = (int*)ws;                    // 400000 B (pad 409600)
    int* off     = (int*)(ws + 409600);         // 400000 B (pad 409600)
    int* counter = (int*)(ws + 819200);         // 256 B
    unsigned short* wt1 = (unsigned short*)(ws + 819456);
    unsigned short* wt2 = wt1 + 16384;
    unsigned short* wt3 = wt2 + 16384;          // ends ~897 KB
    int4* srt = (int4*)(ws + 901120);           // 25.6 MB

    hipMemsetAsync(out, 0, (size_t)out_size * sizeof(float), stream);
    hipMemsetAsync(cnt, 0, (size_t)NN * sizeof(int), stream);
    hipMemsetAsync(counter, 0, sizeof(int), stream);
    prep_kernel<<<152, 256, 0, stream>>>(W1, W2, W3, wt1, wt2, wt3);
    hist_kernel<<<6250, 256, 0, stream>>>(ei, cnt);
    scan_kernel<<<391, 256, 0, stream>>>(cnt, off, counter);
    place_kernel<<<6250, 256, 0, stream>>>(ei, off, srt);
    gemm_kernel<<<256, 512, 0, stream>>>(x, ef, srt, wt1, wt2, wt3, b1, b2, out);
    finalize_kernel<<<NN * NF / 256, 256, 0, stream>>>(x, cnt, b3, out);
}